// Round 1
// baseline (11750.204 us; speedup 1.0000x reference)
//
#include <hip/hip_runtime.h>
#include <math.h>

// ---------------- problem constants ----------------
#define B_    16
#define C_    3
#define HIMG  128
#define PTCH  8
#define E_    512
#define NH_   8
#define P_    64
#define HID_  2048
#define S_    257          // tokens + cond
#define T_    256          // patch tokens
#define MTOK  4096         // B*T
#define MSEQ  4112         // B*S
#define INV_SQRT_E 0.044194173824159216f

// ---------------- tiled fp32 GEMM core ----------------
// C[m,n] = (sum_k A[m,k]*B[k,n]) * scale (+ bias[n]) (leaky 0.2 optional)
// A row-major (lda). B: BT=false -> row-major KxN (ldb); BT=true -> B is NxK
// row-major (ldb), i.e. we multiply by B^T.
#define BM 64
#define BN 64
#define BK 16

template<bool BT, bool LEAKY>
__device__ __forceinline__ void gemm_block(
    const float* __restrict__ A, int lda,
    const float* __restrict__ Bm, int ldb,
    float* __restrict__ C, int ldc,
    const float* __restrict__ bias, float scale,
    int M, int N, int K, int tm, int tn)
{
    __shared__ float As[BK][BM + 4];
    __shared__ float Bs[BK][BN + 4];

    const int tid = threadIdx.x;       // 256 threads
    const int tx  = tid & 15;
    const int ty  = tid >> 4;
    const int m0  = tm * BM;
    const int n0  = tn * BN;

    float acc[4][4] = {};

    for (int k0 = 0; k0 < K; k0 += BK) {
        // ---- load A tile (BM x BK) ----
        {
            const int row = tid >> 2;            // 0..63
            const int kq  = (tid & 3) * 4;       // 0,4,8,12
            const int m   = m0 + row;
#pragma unroll
            for (int j = 0; j < 4; ++j) {
                const int k = k0 + kq + j;
                As[kq + j][row] = (m < M && k < K) ? A[(long)m * lda + k] : 0.f;
            }
        }
        // ---- load B tile (BK x BN) ----
        if (!BT) {
#pragma unroll
            for (int r = 0; r < 4; ++r) {
                const int pos = tid + r * 256;   // 0..1023
                const int kk  = pos >> 6;
                const int nn  = pos & 63;
                const int k   = k0 + kk;
                const int n   = n0 + nn;
                Bs[kk][nn] = (k < K && n < N) ? Bm[(long)k * ldb + n] : 0.f;
            }
        } else {
            const int nn = tid >> 2;             // 0..63
            const int kq = (tid & 3) * 4;
            const int n  = n0 + nn;
#pragma unroll
            for (int j = 0; j < 4; ++j) {
                const int k = k0 + kq + j;
                Bs[kq + j][nn] = (n < N && k < K) ? Bm[(long)n * ldb + k] : 0.f;
            }
        }
        __syncthreads();

#pragma unroll
        for (int kk = 0; kk < BK; ++kk) {
            float a[4], b[4];
#pragma unroll
            for (int i = 0; i < 4; ++i) a[i] = As[kk][ty * 4 + i];
#pragma unroll
            for (int j = 0; j < 4; ++j) b[j] = Bs[kk][tx * 4 + j];
#pragma unroll
            for (int i = 0; i < 4; ++i)
#pragma unroll
                for (int j = 0; j < 4; ++j)
                    acc[i][j] += a[i] * b[j];
        }
        __syncthreads();
    }

#pragma unroll
    for (int i = 0; i < 4; ++i) {
        const int m = m0 + ty * 4 + i;
        if (m >= M) continue;
#pragma unroll
        for (int j = 0; j < 4; ++j) {
            const int n = n0 + tx * 4 + j;
            if (n >= N) continue;
            float v = acc[i][j] * scale;
            if (bias) v += bias[n];
            if (LEAKY) v = v > 0.f ? v : 0.2f * v;
            C[(long)m * ldc + n] = v;
        }
    }
}

// ---------------- flat GEMM wrappers ----------------
template<bool BT, bool LEAKY>
__global__ void gemm_kernel(const float* __restrict__ A, int lda,
                            const float* __restrict__ Bm, int ldb,
                            float* __restrict__ C, int ldc,
                            const float* __restrict__ bias, float scale,
                            int M, int N, int K)
{
    gemm_block<BT, LEAKY>(A, lda, Bm, ldb, C, ldc, bias, scale,
                          M, N, K, blockIdx.x, blockIdx.y);
}

// ---------------- batched attention wrappers ----------------
// k/v proj: out[b,h,s,p] = sum_e z[b,s,e] * w[h,e,p]
__global__ void proj_kernel(const float* __restrict__ z,
                            const float* __restrict__ w,
                            float* __restrict__ out)
{
    const int bh = blockIdx.z;
    const int b  = bh >> 3;
    const int h  = bh & 7;
    gemm_block<false, false>(z + (long)b * S_ * E_, E_,
                             w + (long)h * E_ * P_, P_,
                             out + (long)bh * S_ * P_, P_,
                             nullptr, 1.f, S_, P_, E_, blockIdx.x, 0);
}

// qv: out[b,h,s,p] = sum_t qh[h,s,t] * v[b,h,t,p]
__global__ void qv_kernel(const float* __restrict__ qh,
                          const float* __restrict__ v,
                          float* __restrict__ out)
{
    const int bh = blockIdx.z;
    const int h  = bh & 7;
    gemm_block<false, false>(qh + (long)h * S_ * S_, S_,
                             v + (long)bh * S_ * P_, P_,
                             out + (long)bh * S_ * P_, P_,
                             nullptr, 1.f, S_, P_, S_, blockIdx.x, 0);
}

// scores: a[b,h,i,j] = (k[b,h,i,:] . qv[b,h,j,:]) * scale
__global__ void scores_kernel(const float* __restrict__ k,
                              const float* __restrict__ qv,
                              float* __restrict__ a)
{
    const int bh = blockIdx.z;
    gemm_block<true, false>(k + (long)bh * S_ * P_, P_,
                            qv + (long)bh * S_ * P_, P_,
                            a + (long)bh * S_ * S_, S_,
                            nullptr, INV_SQRT_E, S_, S_, P_, blockIdx.x, blockIdx.y);
}

// o: ocat[b,s,h*P+p] = sum_j a[b,h,s,j] * v[b,h,j,p]
__global__ void av_kernel(const float* __restrict__ a,
                          const float* __restrict__ v,
                          float* __restrict__ ocat)
{
    const int bh = blockIdx.z;
    const int b  = bh >> 3;
    const int h  = bh & 7;
    gemm_block<false, false>(a + (long)bh * S_ * S_, S_,
                             v + (long)bh * S_ * P_, P_,
                             ocat + (long)b * S_ * (NH_ * P_) + h * P_, NH_ * P_,
                             nullptr, 1.f, S_, P_, S_, blockIdx.x, 0);
}

// ---------------- reductions ----------------
__device__ __forceinline__ float block_reduce(float v, bool ismax)
{
    __shared__ float s[8];
#pragma unroll
    for (int o = 32; o > 0; o >>= 1) {
        const float ov = __shfl_down(v, o);
        v = ismax ? fmaxf(v, ov) : v + ov;
    }
    const int w = threadIdx.x >> 6;
    __syncthreads();
    if ((threadIdx.x & 63) == 0) s[w] = v;
    __syncthreads();
    const int nw = blockDim.x >> 6;
    float r = s[0];
    for (int i = 1; i < nw; ++i) r = ismax ? fmaxf(r, s[i]) : r + s[i];
    return r;
}

// softmax over rows of width S_ (=257), in place. grid = B*NH*S, block = 256
__global__ void softmax_kernel(float* __restrict__ a)
{
    const long row = blockIdx.x;
    float* p = a + row * S_;
    const int t = threadIdx.x;
    const float v0 = p[t];
    const float v1 = (t == 0) ? p[256] : -1e30f;
    const float mx = block_reduce(fmaxf(v0, v1), true);
    const float e0 = __expf(v0 - mx);
    const float e1 = (t == 0) ? __expf(v1 - mx) : 0.f;
    const float sum = block_reduce(e0 + e1, false);
    const float inv = 1.f / sum;
    p[t] = e0 * inv;
    if (t == 0) p[256] = e1 * inv;
}

// LayerNorm over E_=512: out[row] = LN(x[xrow] (+ r[row])) * g + b
// skip_cond: xrow = row + (row>>8) + 1 (drops cond token), else xrow = row
__global__ void ln_kernel(const float* __restrict__ x,
                          const float* __restrict__ r,
                          const float* __restrict__ g,
                          const float* __restrict__ bb,
                          float* __restrict__ out, int skip_cond)
{
    const int row = blockIdx.x;
    const long xrow = skip_cond ? (long)row + (row >> 8) + 1 : (long)row;
    const int t = threadIdx.x;   // 256
    const float* xr = x + xrow * E_;
    float v0 = xr[t], v1 = xr[t + 256];
    if (r) {
        const float* rr = r + (long)row * E_;
        v0 += rr[t]; v1 += rr[t + 256];
    }
    const float mean = block_reduce(v0 + v1, false) * (1.f / 512.f);
    const float d0 = v0 - mean, d1 = v1 - mean;
    const float var = block_reduce(d0 * d0 + d1 * d1, false) * (1.f / 512.f);
    const float inv = rsqrtf(var + 1e-5f);
    out[(long)row * E_ + t]       = d0 * inv * g[t] + bb[t];
    out[(long)row * E_ + t + 256] = d1 * inv * g[t + 256] + bb[t + 256];
}

// ---------------- data movement ----------------
// im2col: xcol[(b*256+ph*16+pw)*192 + c*64+p*8+q] = x[b,c,ph*8+p,pw*8+q]
__global__ void im2col_kernel(const float* __restrict__ x, float* __restrict__ xcol)
{
    const int idx = blockIdx.x * 256 + threadIdx.x;
    if (idx >= MTOK * 192) return;
    const int m = idx / 192, k = idx % 192;
    const int b = m >> 8, t = m & 255;
    const int ph = t >> 4, pw = t & 15;
    const int c = k >> 6, rr = k & 63;
    const int p = rr >> 3, q = rr & 7;
    xcol[idx] = x[(((long)(b * C_ + c) * HIMG) + ph * 8 + p) * HIMG + pw * 8 + q];
}

// cond MLP (two layers fused) + pos, writes z row 0 of each batch
__global__ void cond_kernel(const float* __restrict__ y,
                            const float* __restrict__ w1, const float* __restrict__ b1,
                            const float* __restrict__ w2, const float* __restrict__ b2,
                            const float* __restrict__ pos, float* __restrict__ z)
{
    __shared__ float c1[512];
    const int b = blockIdx.x;
    const int e = threadIdx.x;   // 512 threads
    float v = y[b * 3 + 0] * w1[e] + y[b * 3 + 1] * w1[512 + e]
            + y[b * 3 + 2] * w1[1024 + e] + b1[e];
    v = v > 0.f ? v : 0.2f * v;
    c1[e] = v;
    __syncthreads();
    float acc = b2[e];
    for (int k = 0; k < 512; ++k) acc += c1[k] * w2[k * 512 + e];
    acc = acc > 0.f ? acc : 0.2f * acc;
    z[(long)b * S_ * E_ + e] = acc + pos[e];
}

// assemble: z[b,1+t,e] = tok[(b*256+t)*512+e] + pos[(1+t)*512+e]
__global__ void assemble_kernel(const float* __restrict__ tok,
                                const float* __restrict__ pos,
                                float* __restrict__ z)
{
    const int idx = blockIdx.x * 256 + threadIdx.x;
    if (idx >= MTOK * E_) return;
    const int m = idx >> 9;          // b*256+t
    const int e = idx & 511;
    const int b = m >> 8, t = m & 255;
    z[((long)b * S_ + 1 + t) * E_ + e] = tok[idx] + pos[(1 + t) * E_ + e];
}

// scatter: out[b,c,ph*8+p,pw*8+q] = dtmp[(b*256+ph*16+pw)*192 + c*64+p*8+q] + db[c]
__global__ void scatter_kernel(const float* __restrict__ dtmp,
                               const float* __restrict__ db,
                               float* __restrict__ out)
{
    const int idx = blockIdx.x * 256 + threadIdx.x;
    if (idx >= B_ * C_ * HIMG * HIMG) return;
    const int b  = idx / (C_ * HIMG * HIMG);
    const int rm = idx % (C_ * HIMG * HIMG);
    const int c  = rm / (HIMG * HIMG);
    const int hh = (rm % (HIMG * HIMG)) / HIMG;
    const int ww = rm % HIMG;
    const int ph = hh >> 3, p = hh & 7;
    const int pw = ww >> 3, q = ww & 7;
    out[idx] = dtmp[((long)(b * 256 + ph * 16 + pw)) * 192 + c * 64 + p * 8 + q] + db[c];
}

// ---------------- host launch ----------------
extern "C" void kernel_launch(void* const* d_in, const int* in_sizes, int n_in,
                              void* d_out, int out_size, void* d_ws, size_t ws_size,
                              hipStream_t stream)
{
    const float* x        = (const float*)d_in[0];
    const float* y        = (const float*)d_in[1];
    const float* patch_w  = (const float*)d_in[2];
    const float* patch_b  = (const float*)d_in[3];
    const float* cond_w1  = (const float*)d_in[4];
    const float* cond_b1  = (const float*)d_in[5];
    const float* cond_w2  = (const float*)d_in[6];
    const float* cond_b2  = (const float*)d_in[7];
    const float* pos      = (const float*)d_in[8];
    const float* enc_vp   = (const float*)d_in[9];
    const float* enc_kp   = (const float*)d_in[10];
    const float* enc_qh   = (const float*)d_in[11];
    const float* enc_lift = (const float*)d_in[12];
    const float* enc_ln1g = (const float*)d_in[13];
    const float* enc_ln1b = (const float*)d_in[14];
    const float* enc_w1   = (const float*)d_in[15];
    const float* enc_b1   = (const float*)d_in[16];
    const float* enc_w2   = (const float*)d_in[17];
    const float* enc_b2   = (const float*)d_in[18];
    const float* enc_ln2g = (const float*)d_in[19];
    const float* enc_ln2b = (const float*)d_in[20];
    const float* dec_vp   = (const float*)d_in[21];
    const float* dec_kp   = (const float*)d_in[22];
    const float* dec_qh   = (const float*)d_in[23];
    const float* dec_lift = (const float*)d_in[24];
    const float* dec_ln2g = (const float*)d_in[25];
    const float* dec_ln2b = (const float*)d_in[26];
    const float* dec_w1   = (const float*)d_in[27];
    const float* dec_b1   = (const float*)d_in[28];
    const float* dec_w2   = (const float*)d_in[29];
    const float* dec_b2   = (const float*)d_in[30];
    const float* dec_ln3g = (const float*)d_in[31];
    const float* dec_ln3b = (const float*)d_in[32];
    const float* final_g  = (const float*)d_in[33];
    const float* final_b  = (const float*)d_in[34];
    const float* deconv_w = (const float*)d_in[35];
    const float* deconv_b = (const float*)d_in[36];
    float* out = (float*)d_out;

    // workspace layout (floats)
    float* ws   = (float*)d_ws;
    float* z    = ws;                      // 2,105,344  (B*S*E)
    float* xcol = z    + 2105344;          //   786,432  (also deconv tmp)
    float* tok  = xcol + 786432;           // 2,097,152  (also final-LN grid)
    float* kbuf = tok  + 2097152;          // 2,105,344
    float* vbuf = kbuf + 2105344;          // 2,105,344
    float* qvb  = vbuf + 2105344;          // 2,105,344  (also xatt)
    float* attn = qvb  + 2105344;          // 8,454,272  (also FF hidden)
    float* ocat = attn + 8454272;          // 2,105,344
    float* ffo  = ocat + 2105344;          // 2,105,344

    const dim3 blk(256);

    // patch embedding
    im2col_kernel<<<dim3((MTOK * 192 + 255) / 256), blk, 0, stream>>>(x, xcol);
    gemm_kernel<true, false><<<dim3(64, 8), blk, 0, stream>>>(
        xcol, 192, patch_w, 192, tok, 512, patch_b, 1.f, MTOK, 512, 192);
    cond_kernel<<<dim3(B_), dim3(512), 0, stream>>>(y, cond_w1, cond_b1,
                                                    cond_w2, cond_b2, pos, z);
    assemble_kernel<<<dim3((MTOK * E_ + 255) / 256), blk, 0, stream>>>(tok, pos, z);

    for (int l = 0; l < 12; ++l) {
        const bool enc = l < 6;
        const int  li  = enc ? l : l - 6;
        const float* vp   = (enc ? enc_vp   : dec_vp)   + (long)li * NH_ * E_ * P_;
        const float* kp   = (enc ? enc_kp   : dec_kp)   + (long)li * NH_ * E_ * P_;
        const float* qh   = (enc ? enc_qh   : dec_qh)   + (long)li * NH_ * S_ * S_;
        const float* lift = (enc ? enc_lift : dec_lift) + (long)li * 512 * 512;
        const float* g1   = (enc ? enc_ln1g : dec_ln2g) + li * E_;
        const float* bb1  = (enc ? enc_ln1b : dec_ln2b) + li * E_;
        const float* w1   = (enc ? enc_w1   : dec_w1)   + (long)li * E_ * HID_;
        const float* fb1  = (enc ? enc_b1   : dec_b1)   + li * HID_;
        const float* w2   = (enc ? enc_w2   : dec_w2)   + (long)li * HID_ * E_;
        const float* fb2  = (enc ? enc_b2   : dec_b2)   + li * E_;
        const float* g2   = (enc ? enc_ln2g : dec_ln3g) + li * E_;
        const float* bb2  = (enc ? enc_ln2b : dec_ln3b) + li * E_;

        proj_kernel<<<dim3(5, 1, 128), blk, 0, stream>>>(z, kp, kbuf);
        proj_kernel<<<dim3(5, 1, 128), blk, 0, stream>>>(z, vp, vbuf);
        qv_kernel<<<dim3(5, 1, 128), blk, 0, stream>>>(qh, vbuf, qvb);
        scores_kernel<<<dim3(5, 5, 128), blk, 0, stream>>>(kbuf, qvb, attn);
        softmax_kernel<<<dim3(B_ * NH_ * S_), blk, 0, stream>>>(attn);
        av_kernel<<<dim3(5, 1, 128), blk, 0, stream>>>(attn, vbuf, ocat);
        gemm_kernel<false, false><<<dim3(65, 8), blk, 0, stream>>>(
            ocat, 512, lift, 512, qvb, 512, nullptr, 1.f, MSEQ, 512, 512);
        ln_kernel<<<dim3(MSEQ), blk, 0, stream>>>(z, qvb, g1, bb1, z, 0);
        gemm_kernel<false, true><<<dim3(65, 32), blk, 0, stream>>>(
            z, 512, w1, HID_, attn, HID_, fb1, 1.f, MSEQ, HID_, 512);
        gemm_kernel<false, false><<<dim3(65, 8), blk, 0, stream>>>(
            attn, HID_, w2, 512, ffo, 512, fb2, 1.f, MSEQ, 512, HID_);
        ln_kernel<<<dim3(MSEQ), blk, 0, stream>>>(z, ffo, g2, bb2, z, 0);
    }

    // final LN (drop cond token) -> grid buffer (tok)
    ln_kernel<<<dim3(MTOK), blk, 0, stream>>>(z, nullptr, final_g, final_b, tok, 1);
    // deconv GEMM -> dtmp (xcol), then scatter + bias
    gemm_kernel<false, false><<<dim3(64, 3), blk, 0, stream>>>(
        tok, 512, deconv_w, 192, xcol, 192, nullptr, 1.f, MTOK, 192, 512);
    scatter_kernel<<<dim3((B_ * C_ * HIMG * HIMG + 255) / 256), blk, 0, stream>>>(
        xcol, deconv_b, out);
}

// Round 6
// 2753.996 us; speedup vs baseline: 4.2666x; 4.2666x over previous
//
#include <hip/hip_runtime.h>
#include <stdint.h>
#include <math.h>

// ---------------- problem constants ----------------
#define B_    16
#define C_    3
#define HIMG  128
#define E_    512
#define NH_   8
#define S_    257
#define T_    256
#define MTOK  4096         // B*T
#define MSEQ  4112         // B*S
#define HID_  2048
#define SP_   288          // S padded to mult of 32
#define SLAB  (288*288)
#define INV_SQRT_E 0.044194173824159216f

typedef __attribute__((ext_vector_type(8))) __bf16 bf16x8;
typedef __attribute__((ext_vector_type(4))) float f32x4;

// ---------------- global->LDS direct (16B/lane) ----------------
__device__ __forceinline__ void gload16(const void* g, const void* lds)
{
    __builtin_amdgcn_global_load_lds(
        (const __attribute__((address_space(1))) uint32_t*)(uintptr_t)g,
        (__attribute__((address_space(3))) uint32_t*)(uint32_t)(uintptr_t)lds,
        16, 0, 0);
}

// ---------------- bf16 MFMA GEMM core ----------------
// C[M,N] = scale * (A[M,K] . Bt[N,K]^T) (+bias[n]) (leaky opt)
// A, Bt bf16 row-major. BM=128, BN=WN*32, BK=32, 256 threads = 4 waves (2x2).
// LDS layout: [row][chunk^((row>>1)&3)] of 16B chunks (4/row) -> 2-way-free reads.
// Staging rows beyond M must be readable (callers pad allocations);
// K must be a multiple of 32 with zero-padded operands where applicable.
template<int WN, bool LEAKY, bool OUTF32>
__device__ __forceinline__ void gemm_core(
    const __bf16* __restrict__ A, int lda,
    const __bf16* __restrict__ Bt, int ldb,
    void* __restrict__ C, int ldc,
    const float* __restrict__ bias, float scale,
    int M, int N, int K, int tm, int tn)
{
    constexpr int BM = 128;
    constexpr int BN = WN * 32;
    __shared__ __align__(16) __bf16 sA[BM * 32];
    __shared__ __align__(16) __bf16 sB[BN * 32];

    const int tid  = threadIdx.x;
    const int lane = tid & 63;
    const int wid  = tid >> 6;
    const int wm   = wid >> 1;          // wave row 0..1
    const int wn   = wid & 1;           // wave col 0..1
    const int lh   = lane >> 4;         // k-group 0..3
    const int ll   = lane & 15;

    f32x4 acc[4][WN] = {};

    for (int k0 = 0; k0 < K; k0 += 32) {
#pragma unroll
        for (int r = 0; r < BM / 64; ++r) {          // A: BM rows x 64B
            const int L   = r * 256 + tid;
            const int row = L >> 2;
            const int gch = (L & 3) ^ ((row >> 1) & 3);
            gload16(A + (long)(tm * BM + row) * lda + k0 + gch * 8,
                    (const char*)sA + (r * 256 + (wid << 6)) * 16);
        }
#pragma unroll
        for (int r = 0; r < BN / 64; ++r) {          // B: BN rows x 64B
            const int L   = r * 256 + tid;
            const int row = L >> 2;
            const int gch = (L & 3) ^ ((row >> 1) & 3);
            gload16(Bt + (long)(tn * BN + row) * ldb + k0 + gch * 8,
                    (const char*)sB + (r * 256 + (wid << 6)) * 16);
        }
        __syncthreads();   // compiler drains vmcnt before barrier

        bf16x8 afr[4], bfr[WN];
#pragma unroll
        for (int i = 0; i < 4; ++i) {
            const int r = wm * 64 + i * 16 + ll;
            const int c = lh ^ ((r >> 1) & 3);
            afr[i] = *reinterpret_cast<const bf16x8*>(&sA[r * 32 + c * 8]);
        }
#pragma unroll
        for (int j = 0; j < WN; ++j) {
            const int r = wn * (WN * 16) + j * 16 + ll;
            const int c = lh ^ ((r >> 1) & 3);
            bfr[j] = *reinterpret_cast<const bf16x8*>(&sB[r * 32 + c * 8]);
        }
#pragma unroll
        for (int i = 0; i < 4; ++i)
#pragma unroll
            for (int j = 0; j < WN; ++j)
                acc[i][j] = __builtin_amdgcn_mfma_f32_16x16x32_bf16(
                                afr[i], bfr[j], acc[i][j], 0, 0, 0);
        __syncthreads();
    }

    // epilogue: D frag col=lane&15, row=(lane>>4)*4+reg  [m89-verified]
#pragma unroll
    for (int i = 0; i < 4; ++i) {
#pragma unroll
        for (int ii = 0; ii < 4; ++ii) {
            const int m = tm * BM + wm * 64 + i * 16 + lh * 4 + ii;
            if (m >= M) continue;
#pragma unroll
            for (int j = 0; j < WN; ++j) {
                const int n = tn * BN + wn * (WN * 16) + j * 16 + ll;
                if (n >= N) continue;
                float v = acc[i][j][ii] * scale;
                if (bias) v += bias[n];
                if (LEAKY) v = v > 0.f ? v : 0.2f * v;
                if (OUTF32) ((float*)C)[(long)m * ldc + n] = v;
                else        ((__bf16*)C)[(long)m * ldc + n] = (__bf16)v;
            }
        }
    }
}

template<int WN, bool LEAKY, bool OUTF32>
__global__ __launch_bounds__(256) void gemm_k(
    const __bf16* __restrict__ A, int lda, const __bf16* __restrict__ Bt, int ldb,
    void* __restrict__ C, int ldc, const float* __restrict__ bias, float scale,
    int M, int N, int K)
{
    gemm_core<WN, LEAKY, OUTF32>(A, lda, Bt, ldb, C, ldc, bias, scale,
                                 M, N, K, blockIdx.x, blockIdx.y);
}

// ---------------- batched attention GEMM wrappers ----------------
// qv: qv[b,s,(h,p)] = sum_t qh[h,s,t] * v[b,t,(h,p)]
__global__ __launch_bounds__(256) void qv_k(const __bf16* __restrict__ qhb,
                                            const __bf16* __restrict__ vT,
                                            __bf16* __restrict__ qvcat)
{
    const int bh = blockIdx.z, b = bh >> 3, h = bh & 7;
    gemm_core<2, false, false>(qhb + (long)h * SLAB, SP_,
                               vT + (long)bh * 64 * SP_, SP_,
                               qvcat + (long)b * S_ * E_ + h * 64, E_,
                               nullptr, 1.f, S_, 64, SP_, blockIdx.x, 0);
}

// scores: a[i,j] = scale * k[b,h,i,:] . qv[b,h,j,:]
__global__ __launch_bounds__(256) void scores_k(const __bf16* __restrict__ kcat,
                                                const __bf16* __restrict__ qvcat,
                                                __bf16* __restrict__ attnb)
{
    const int bh = blockIdx.z, b = bh >> 3, h = bh & 7;
    gemm_core<4, false, false>(kcat + (long)b * S_ * E_ + h * 64, E_,
                               qvcat + (long)b * S_ * E_ + h * 64, E_,
                               attnb + (long)bh * SLAB, SP_,
                               nullptr, INV_SQRT_E, S_, S_, 64, blockIdx.x, blockIdx.y);
}

// av: o[i,(h,p)] = sum_j a[i,j] * v[b,j,(h,p)]
__global__ __launch_bounds__(256) void av_k(const __bf16* __restrict__ attnb,
                                            const __bf16* __restrict__ vT,
                                            __bf16* __restrict__ ocat)
{
    const int bh = blockIdx.z, b = bh >> 3, h = bh & 7;
    gemm_core<2, false, false>(attnb + (long)bh * SLAB, SP_,
                               vT + (long)bh * 64 * SP_, SP_,
                               ocat + (long)b * S_ * E_ + h * 64, E_,
                               nullptr, 1.f, S_, 64, SP_, blockIdx.x, 0);
}

// ---------------- reductions ----------------
__device__ __forceinline__ float block_reduce(float v, bool ismax)
{
    __shared__ float s[8];
#pragma unroll
    for (int o = 32; o > 0; o >>= 1) {
        const float ov = __shfl_down(v, o);
        v = ismax ? fmaxf(v, ov) : v + ov;
    }
    const int w = threadIdx.x >> 6;
    __syncthreads();
    if ((threadIdx.x & 63) == 0) s[w] = v;
    __syncthreads();
    const int nw = blockDim.x >> 6;
    float r = s[0];
    for (int i = 1; i < nw; ++i) r = ismax ? fmaxf(r, s[i]) : r + s[i];
    return r;
}

// softmax over 257-wide rows of bf16 attn slabs; writes zeros into K-pad cols
__global__ void softmax_kernel(__bf16* __restrict__ attnb)
{
    const int rowid = blockIdx.x;
    const int bh = rowid / S_, s = rowid % S_;
    __bf16* p = attnb + (long)bh * SLAB + (long)s * SP_;
    const int t = threadIdx.x;
    const float v0 = (float)p[t];
    const float v1 = (t == 0) ? (float)p[256] : -1e30f;
    const float mx = block_reduce(fmaxf(v0, v1), true);
    const float e0 = __expf(v0 - mx);
    const float e1 = (t == 0) ? __expf(v1 - mx) : 0.f;
    const float sum = block_reduce(e0 + e1, false);
    const float inv = 1.f / sum;
    p[t] = (__bf16)(e0 * inv);
    if (t == 0) p[256] = (__bf16)(e1 * inv);
    if (t >= 1 && t < 32) p[256 + t] = (__bf16)0.f;   // zero K-pad
}

// LayerNorm over E=512; optional residual add; writes fp32 and/or bf16 outs
__global__ void ln_kernel(const float* __restrict__ x, const float* __restrict__ r,
                          const float* __restrict__ g, const float* __restrict__ bb,
                          float* __restrict__ outf, __bf16* __restrict__ outb,
                          int skip_cond)
{
    const int row = blockIdx.x;
    const long xrow = skip_cond ? (long)row + (row >> 8) + 1 : (long)row;
    const int t = threadIdx.x;   // 256
    const float* xr = x + xrow * E_;
    float v0 = xr[t], v1 = xr[t + 256];
    if (r) { const float* rr = r + (long)row * E_; v0 += rr[t]; v1 += rr[t + 256]; }
    const float mean = block_reduce(v0 + v1, false) * (1.f / 512.f);
    const float d0 = v0 - mean, d1 = v1 - mean;
    const float var = block_reduce(d0 * d0 + d1 * d1, false) * (1.f / 512.f);
    const float inv = rsqrtf(var + 1e-5f);
    const float o0 = d0 * inv * g[t] + bb[t];
    const float o1 = d1 * inv * g[t + 256] + bb[t + 256];
    if (outf) { outf[(long)row * E_ + t] = o0; outf[(long)row * E_ + t + 256] = o1; }
    if (outb) { outb[(long)row * E_ + t] = (__bf16)o0; outb[(long)row * E_ + t + 256] = (__bf16)o1; }
}

// ---------------- converts / data movement ----------------
__global__ void conv_straight(const float* __restrict__ in, __bf16* __restrict__ out, long n)
{
    const long i = (long)blockIdx.x * 256 + threadIdx.x;
    if (i < n) out[i] = (__bf16)in[i];
}

// LDS-tiled transpose: out[bt][c*R + r] = in[bt][r*C + c]  (fp32 -> bf16)
// grid: (ceil(R/32), ceil(C/32), batches), block: 256
__global__ void conv_transpose(const float* __restrict__ in, __bf16* __restrict__ out,
                               int R, int C, long in_bs, long out_bs)
{
    __shared__ float tile[32][33];
    const int bt = blockIdx.z;
    const float* ip = in + (long)bt * in_bs;
    __bf16* op = out + (long)bt * out_bs;
    const int r0 = blockIdx.x * 32, c0 = blockIdx.y * 32;
    const int tx = threadIdx.x & 31, ty = threadIdx.x >> 5;   // ty: 0..7
#pragma unroll
    for (int i = 0; i < 32; i += 8) {
        const int r = r0 + ty + i, c = c0 + tx;
        tile[ty + i][tx] = (r < R && c < C) ? ip[(long)r * C + c] : 0.f;
    }
    __syncthreads();
#pragma unroll
    for (int i = 0; i < 32; i += 8) {
        const int c = c0 + ty + i, r = r0 + tx;
        if (c < C && r < R) op[(long)c * R + r] = (__bf16)tile[tx][ty + i];
    }
}

// qh (8,257,257) fp32 -> (8,288,288) bf16 zero-padded slabs
__global__ void conv_qh(const float* __restrict__ qh, __bf16* __restrict__ out)
{
    const long n = 8L * SLAB;
    for (long o = (long)blockIdx.x * 256 + threadIdx.x; o < n; o += (long)gridDim.x * 256) {
        const int t = (int)(o % SP_);
        const long rr = o / SP_;
        const int s = (int)(rr % SP_);
        const int h = (int)(rr / SP_);
        float v = 0.f;
        if (s < S_ && t < S_) v = qh[((long)h * S_ + s) * S_ + t];
        out[o] = (__bf16)v;
    }
}

// vT[bh][p][t] = vcat[b*257+t][h*64+p], zero for t>=257
__global__ void vtrans_kernel(const __bf16* __restrict__ vcat, __bf16* __restrict__ vT)
{
    const int bh = blockIdx.y, b = bh >> 3, h = bh & 7;
    for (int o = blockIdx.x * 256 + threadIdx.x; o < 64 * SP_; o += gridDim.x * 256) {
        const int t = o % SP_, p = o / SP_;
        __bf16 v = (__bf16)0.f;
        if (t < S_) v = vcat[((long)(b * S_ + t)) * E_ + h * 64 + p];
        vT[(long)bh * 64 * SP_ + o] = v;
    }
}

// im2col -> bf16: xcol[(b*256+ph*16+pw)*192 + c*64+p*8+q] = x[b,c,ph*8+p,pw*8+q]
__global__ void im2col_kernel(const float* __restrict__ x, __bf16* __restrict__ xcol)
{
    const int idx = blockIdx.x * 256 + threadIdx.x;
    if (idx >= MTOK * 192) return;
    const int m = idx / 192, k = idx % 192;
    const int b = m >> 8, t = m & 255;
    const int ph = t >> 4, pw = t & 15;
    const int c = k >> 6, rr = k & 63;
    const int p = rr >> 3, q = rr & 7;
    xcol[idx] = (__bf16)x[(((long)(b * C_ + c) * HIMG) + ph * 8 + p) * HIMG + pw * 8 + q];
}

// cond MLP (two layers) + pos -> z row 0 (fp32 + bf16)
__global__ void cond_kernel(const float* __restrict__ y,
                            const float* __restrict__ w1, const float* __restrict__ b1,
                            const float* __restrict__ w2, const float* __restrict__ b2,
                            const float* __restrict__ pos,
                            float* __restrict__ z, __bf16* __restrict__ zb)
{
    __shared__ float c1[512];
    const int b = blockIdx.x;
    const int e = threadIdx.x;   // 512
    float v = y[b * 3 + 0] * w1[e] + y[b * 3 + 1] * w1[512 + e]
            + y[b * 3 + 2] * w1[1024 + e] + b1[e];
    v = v > 0.f ? v : 0.2f * v;
    c1[e] = v;
    __syncthreads();
    float acc = b2[e];
    for (int k = 0; k < 512; ++k) acc += c1[k] * w2[k * 512 + e];
    acc = acc > 0.f ? acc : 0.2f * acc;
    const float o = acc + pos[e];
    z[(long)b * S_ * E_ + e] = o;
    zb[(long)b * S_ * E_ + e] = (__bf16)o;
}

// z[b,1+t,e] = tok[(b*256+t)*512+e] + pos[(1+t)*512+e]  (fp32 + bf16)
__global__ void assemble_kernel(const float* __restrict__ tok,
                                const float* __restrict__ pos,
                                float* __restrict__ z, __bf16* __restrict__ zb)
{
    const int idx = blockIdx.x * 256 + threadIdx.x;
    if (idx >= MTOK * E_) return;
    const int m = idx >> 9;
    const int e = idx & 511;
    const int b = m >> 8, t = m & 255;
    const float o = tok[idx] + pos[(1 + t) * E_ + e];
    const long zi = ((long)b * S_ + 1 + t) * E_ + e;
    z[zi] = o;
    zb[zi] = (__bf16)o;
}

// scatter deconv tmp -> (B,C,H,W) + bias
__global__ void scatter_kernel(const float* __restrict__ dtmp,
                               const float* __restrict__ db,
                               float* __restrict__ out)
{
    const int idx = blockIdx.x * 256 + threadIdx.x;
    if (idx >= B_ * C_ * HIMG * HIMG) return;
    const int b  = idx / (C_ * HIMG * HIMG);
    const int rm = idx % (C_ * HIMG * HIMG);
    const int c  = rm / (HIMG * HIMG);
    const int hh = (rm % (HIMG * HIMG)) / HIMG;
    const int ww = rm % HIMG;
    const int ph = hh >> 3, p = hh & 7;
    const int pw = ww >> 3, q = ww & 7;
    out[idx] = dtmp[((long)(b * 256 + ph * 16 + pw)) * 192 + c * 64 + p * 8 + q] + db[c];
}

// ---------------- host launch ----------------
extern "C" void kernel_launch(void* const* d_in, const int* in_sizes, int n_in,
                              void* d_out, int out_size, void* d_ws, size_t ws_size,
                              hipStream_t stream)
{
    const float* x        = (const float*)d_in[0];
    const float* y        = (const float*)d_in[1];
    const float* patch_w  = (const float*)d_in[2];
    const float* patch_b  = (const float*)d_in[3];
    const float* cond_w1  = (const float*)d_in[4];
    const float* cond_b1  = (const float*)d_in[5];
    const float* cond_w2  = (const float*)d_in[6];
    const float* cond_b2  = (const float*)d_in[7];
    const float* pos      = (const float*)d_in[8];
    const float* enc_vp   = (const float*)d_in[9];
    const float* enc_kp   = (const float*)d_in[10];
    const float* enc_qh   = (const float*)d_in[11];
    const float* enc_lift = (const float*)d_in[12];
    const float* enc_ln1g = (const float*)d_in[13];
    const float* enc_ln1b = (const float*)d_in[14];
    const float* enc_w1   = (const float*)d_in[15];
    const float* enc_b1   = (const float*)d_in[16];
    const float* enc_w2   = (const float*)d_in[17];
    const float* enc_b2   = (const float*)d_in[18];
    const float* enc_ln2g = (const float*)d_in[19];
    const float* enc_ln2b = (const float*)d_in[20];
    const float* dec_vp   = (const float*)d_in[21];
    const float* dec_kp   = (const float*)d_in[22];
    const float* dec_qh   = (const float*)d_in[23];
    const float* dec_lift = (const float*)d_in[24];
    const float* dec_ln2g = (const float*)d_in[25];
    const float* dec_ln2b = (const float*)d_in[26];
    const float* dec_w1   = (const float*)d_in[27];
    const float* dec_b1   = (const float*)d_in[28];
    const float* dec_w2   = (const float*)d_in[29];
    const float* dec_b2   = (const float*)d_in[30];
    const float* dec_ln3g = (const float*)d_in[31];
    const float* dec_ln3b = (const float*)d_in[32];
    const float* final_g  = (const float*)d_in[33];
    const float* final_b  = (const float*)d_in[34];
    const float* deconv_w = (const float*)d_in[35];
    const float* deconv_b = (const float*)d_in[36];
    float* out = (float*)d_out;

    // ---- workspace carve-up (16B-aligned) ----
    char* wp = (char*)d_ws;
    auto alloc_f32 = [&](long n) { float* p = (float*)wp; wp += ((n * 4 + 63) & ~63LL); return p; };
    auto alloc_bf  = [&](long n) { __bf16* p = (__bf16*)wp; wp += ((n * 2 + 63) & ~63LL); return p; };

    float*  z      = alloc_f32(2105344);            // (B*S,512) fp32
    float*  tok    = alloc_f32(2097152);            // patch gemm out fp32
    float*  res    = alloc_f32(2105344);            // attn-lift out / ffn2 out fp32
    float*  dtmp   = alloc_f32(786432);             // deconv out fp32
    __bf16* zb     = alloc_bf(4352L * 512);         // bf16 z (padded rows)
    __bf16* xcolb  = alloc_bf(786432);
    __bf16* kcat   = alloc_bf(4352L * 512);
    __bf16* vcat   = alloc_bf(4352L * 512);
    __bf16* qvcat  = alloc_bf(4352L * 512);
    __bf16* ocat   = alloc_bf(4352L * 512);
    __bf16* vT     = alloc_bf(128L * 64 * SP_);
    __bf16* attnb  = alloc_bf(128L * SLAB + 96L * SP_);
    __bf16* hidden = alloc_bf(4224L * 2048);
    __bf16* gbuf   = alloc_bf(4096L * 512);
    __bf16* pwb    = alloc_bf(512L * 192);
    __bf16* dwTb   = alloc_bf(192L * 512);
    __bf16* kpTb   = alloc_bf(262144);              // per-layer reused
    __bf16* vpTb   = alloc_bf(262144);
    __bf16* liftTb = alloc_bf(262144);
    __bf16* w1Tb   = alloc_bf(1048576);             // (2048,512)
    __bf16* w2Tb   = alloc_bf(1048576);             // (512,2048)
    __bf16* qhb    = alloc_bf(8L * SLAB + 96L * SP_);
    (void)ws_size; (void)in_sizes; (void)n_in; (void)out_size;

    const dim3 blk(256);

    // ---- static weight converts ----
    conv_straight<<<dim3(384), blk, 0, stream>>>(patch_w, pwb, 98304);        // (512,192) N x K
    conv_transpose<<<dim3(16, 6, 1), blk, 0, stream>>>(deconv_w, dwTb, 512, 192, 0, 0);

    // ---- patch embedding + cond + assemble ----
    im2col_kernel<<<dim3(3072), blk, 0, stream>>>(x, xcolb);
    gemm_k<2, false, true><<<dim3(32, 8), blk, 0, stream>>>(
        xcolb, 192, pwb, 192, tok, 512, patch_b, 1.f, MTOK, 512, 192);
    cond_kernel<<<dim3(B_), dim3(512), 0, stream>>>(y, cond_w1, cond_b1,
                                                    cond_w2, cond_b2, pos, z, zb);
    assemble_kernel<<<dim3(8192), blk, 0, stream>>>(tok, pos, z, zb);

    for (int l = 0; l < 12; ++l) {
        const bool enc = l < 6;
        const int  li  = enc ? l : l - 6;
        const float* vp   = (enc ? enc_vp   : dec_vp)   + (long)li * NH_ * E_ * 64;
        const float* kp   = (enc ? enc_kp   : dec_kp)   + (long)li * NH_ * E_ * 64;
        const float* qh   = (enc ? enc_qh   : dec_qh)   + (long)li * NH_ * S_ * S_;
        const float* lift = (enc ? enc_lift : dec_lift) + (long)li * 512 * 512;
        const float* g1   = (enc ? enc_ln1g : dec_ln2g) + li * E_;
        const float* bb1  = (enc ? enc_ln1b : dec_ln2b) + li * E_;
        const float* w1   = (enc ? enc_w1   : dec_w1)   + (long)li * E_ * HID_;
        const float* fb1  = (enc ? enc_b1   : dec_b1)   + li * HID_;
        const float* w2   = (enc ? enc_w2   : dec_w2)   + (long)li * HID_ * E_;
        const float* fb2  = (enc ? enc_b2   : dec_b2)   + li * E_;
        const float* g2   = (enc ? enc_ln2g : dec_ln3g) + li * E_;
        const float* bb2  = (enc ? enc_ln2b : dec_ln3b) + li * E_;

        // per-layer weight converts (bf16, N x K form)
        conv_transpose<<<dim3(16, 2, 8), blk, 0, stream>>>(kp,   kpTb,   512, 64,  32768, 32768);
        conv_transpose<<<dim3(16, 2, 8), blk, 0, stream>>>(vp,   vpTb,   512, 64,  32768, 32768);
        conv_transpose<<<dim3(16, 16, 1), blk, 0, stream>>>(lift, liftTb, 512, 512, 0, 0);
        conv_transpose<<<dim3(16, 64, 1), blk, 0, stream>>>(w1,   w1Tb,   512, 2048, 0, 0);
        conv_transpose<<<dim3(64, 16, 1), blk, 0, stream>>>(w2,   w2Tb,   2048, 512, 0, 0);
        conv_qh<<<dim3(2592), blk, 0, stream>>>(qh, qhb);

        // attention
        gemm_k<2, false, false><<<dim3(33, 8), blk, 0, stream>>>(
            zb, 512, kpTb, 512, kcat, 512, nullptr, 1.f, MSEQ, 512, 512);
        gemm_k<2, false, false><<<dim3(33, 8), blk, 0, stream>>>(
            zb, 512, vpTb, 512, vcat, 512, nullptr, 1.f, MSEQ, 512, 512);
        vtrans_kernel<<<dim3(72, 128), blk, 0, stream>>>(vcat, vT);
        qv_k<<<dim3(3, 1, 128), blk, 0, stream>>>(qhb, vT, qvcat);
        scores_k<<<dim3(3, 3, 128), blk, 0, stream>>>(kcat, qvcat, attnb);
        softmax_kernel<<<dim3(128 * S_), blk, 0, stream>>>(attnb);
        av_k<<<dim3(3, 1, 128), blk, 0, stream>>>(attnb, vT, ocat);
        gemm_k<2, false, true><<<dim3(33, 8), blk, 0, stream>>>(
            ocat, 512, liftTb, 512, res, 512, nullptr, 1.f, MSEQ, 512, 512);
        ln_kernel<<<dim3(MSEQ), blk, 0, stream>>>(z, res, g1, bb1, z, zb, 0);

        // FFN
        gemm_k<4, true, false><<<dim3(33, 16), blk, 0, stream>>>(
            zb, 512, w1Tb, 512, hidden, 2048, fb1, 1.f, MSEQ, HID_, 512);
        gemm_k<2, false, true><<<dim3(33, 8), blk, 0, stream>>>(
            hidden, 2048, w2Tb, 2048, res, 512, fb2, 1.f, MSEQ, 512, HID_);
        ln_kernel<<<dim3(MSEQ), blk, 0, stream>>>(z, res, g2, bb2, z, zb, 0);
    }

    // final LN (drop cond token) -> bf16 grid
    ln_kernel<<<dim3(MTOK), blk, 0, stream>>>(z, nullptr, final_g, final_b,
                                              nullptr, gbuf, 1);
    // deconv GEMM + scatter
    gemm_k<2, false, true><<<dim3(32, 3), blk, 0, stream>>>(
        gbuf, 512, dwTb, 512, dtmp, 192, nullptr, 1.f, MTOK, 192, 512);
    scatter_kernel<<<dim3(3072), blk, 0, stream>>>(dtmp, deconv_b, out);
}

// Round 7
// 1766.044 us; speedup vs baseline: 6.6534x; 1.5594x over previous
//
#include <hip/hip_runtime.h>
#include <stdint.h>
#include <math.h>

// ---------------- problem constants ----------------
#define B_    16
#define C_    3
#define HIMG  128
#define E_    512
#define NH_   8
#define S_    257
#define T_    256
#define MTOK  4096         // B*T
#define MSEQ  4112         // B*S
#define HID_  2048
#define SP_   288          // S padded to mult of 32
#define SLAB  (288*288)
#define INV_SQRT_E 0.044194173824159216f

typedef __attribute__((ext_vector_type(8))) __bf16 bf16x8;
typedef __attribute__((ext_vector_type(4))) float f32x4;

// ---------------- global->LDS direct (16B/lane) ----------------
__device__ __forceinline__ void gload16(const void* g, const void* lds)
{
    __builtin_amdgcn_global_load_lds(
        (const __attribute__((address_space(1))) uint32_t*)(uintptr_t)g,
        (__attribute__((address_space(3))) uint32_t*)(uint32_t)(uintptr_t)lds,
        16, 0, 0);
}

// ---------------- bf16 MFMA GEMM core (double-buffered) ----------------
// C[M,N] = scale * (A[M,K] . Bt[N,K]^T) (+bias[n]) (leaky opt)
// A, Bt bf16 row-major. BM=WMW*64, BN=WNW*32. Wave tile 64x32 (4x2 MFMA frags).
// LDS: [row][chunk^((row>>1)&3)] 16B chunks, pre-swizzled global source.
// 2-phase pipeline: stage(t+1) issued before compute(t); one barrier per step.
// Staged rows beyond M must be readable (callers pad allocations); K % 32 == 0.
template<int WMW, int WNW, bool LEAKY, bool OUTF32>
__device__ __forceinline__ void gemm_core(
    const __bf16* __restrict__ A, int lda,
    const __bf16* __restrict__ Bt, int ldb,
    void* __restrict__ C, int ldc,
    const float* __restrict__ bias, float scale,
    int M, int N, int K, int tm, int tn)
{
    constexpr int BM = WMW * 64;
    constexpr int BN = WNW * 32;
    constexpr int T  = WMW * WNW * 64;
    constexpr int AC = BM * 4;          // 16B chunks per A tile
    constexpr int BC = BN * 4;
    __shared__ __align__(16) __bf16 sA[2][BM * 32];
    __shared__ __align__(16) __bf16 sB[2][BN * 32];

    const int tid  = threadIdx.x;
    const int lane = tid & 63;
    const int wid  = tid >> 6;
    const int wm   = wid / WNW;
    const int wn   = wid % WNW;
    const int lh   = lane >> 4;
    const int ll   = lane & 15;

    const __bf16* Ab = A + (long)tm * BM * lda;
    const __bf16* Bb = Bt + (long)tn * BN * ldb;

    f32x4 acc[4][2] = {};
    const int nst = K >> 5;

    auto stage = [&](int buf, int k0) {
#pragma unroll
        for (int rr = 0; rr < AC / T; ++rr) {
            const int L = rr * T + tid;
            const int row = L >> 2;
            const int gch = (L & 3) ^ ((row >> 1) & 3);
            gload16(Ab + (long)row * lda + k0 + gch * 8,
                    (const char*)(&sA[buf][0]) + (rr * T + (wid << 6)) * 16);
        }
#pragma unroll
        for (int rr = 0; rr < BC / T; ++rr) {
            const int L = rr * T + tid;
            const int row = L >> 2;
            const int gch = (L & 3) ^ ((row >> 1) & 3);
            gload16(Bb + (long)row * ldb + k0 + gch * 8,
                    (const char*)(&sB[buf][0]) + (rr * T + (wid << 6)) * 16);
        }
    };

    stage(0, 0);
    __syncthreads();
    for (int st = 0; st < nst; ++st) {
        const int cur = st & 1;
        if (st + 1 < nst) stage(cur ^ 1, (st + 1) << 5);

        bf16x8 afr[4], bfr[2];
#pragma unroll
        for (int i = 0; i < 4; ++i) {
            const int rw = wm * 64 + i * 16 + ll;
            const int c  = lh ^ ((rw >> 1) & 3);
            afr[i] = *reinterpret_cast<const bf16x8*>(&sA[cur][rw * 32 + c * 8]);
        }
#pragma unroll
        for (int j = 0; j < 2; ++j) {
            const int rw = wn * 32 + j * 16 + ll;
            const int c  = lh ^ ((rw >> 1) & 3);
            bfr[j] = *reinterpret_cast<const bf16x8*>(&sB[cur][rw * 32 + c * 8]);
        }
#pragma unroll
        for (int i = 0; i < 4; ++i)
#pragma unroll
            for (int j = 0; j < 2; ++j)
                acc[i][j] = __builtin_amdgcn_mfma_f32_16x16x32_bf16(
                                afr[i], bfr[j], acc[i][j], 0, 0, 0);
        if (st + 1 < nst) __syncthreads();
    }

    // epilogue: D frag col=lane&15, row=(lane>>4)*4+reg  [m89-verified]
#pragma unroll
    for (int i = 0; i < 4; ++i)
#pragma unroll
        for (int ii = 0; ii < 4; ++ii) {
            const int m = tm * BM + wm * 64 + i * 16 + lh * 4 + ii;
            if (m >= M) continue;
#pragma unroll
            for (int j = 0; j < 2; ++j) {
                const int n = tn * BN + wn * 32 + j * 16 + ll;
                if (n >= N) continue;
                float v = acc[i][j][ii] * scale;
                if (bias) v += bias[n];
                if (LEAKY) v = v > 0.f ? v : 0.2f * v;
                if (OUTF32) ((float*)C)[(long)m * ldc + n] = v;
                else        ((__bf16*)C)[(long)m * ldc + n] = (__bf16)v;
            }
        }
}

// flat-grid GEMM with bijective XCD swizzle (tn fastest within an XCD chunk
// -> A row-panels stay resident in that XCD's private L2)
template<int WMW, int WNW, bool LEAKY, bool OUTF32>
__global__ __launch_bounds__(WMW * WNW * 64) void gemm_k(
    const __bf16* __restrict__ A, int lda, const __bf16* __restrict__ Bt, int ldb,
    void* __restrict__ C, int ldc, const float* __restrict__ bias, float scale,
    int M, int N, int K, int ntn)
{
    const int nwg = gridDim.x;
    int wg = blockIdx.x;
    const int q = nwg >> 3, r = nwg & 7;
    if (q > 0) {
        const int xcd = wg & 7, off = wg >> 3;
        wg = (xcd < r ? xcd * (q + 1) : r * (q + 1) + (xcd - r) * q) + off;
    }
    gemm_core<WMW, WNW, LEAKY, OUTF32>(A, lda, Bt, ldb, C, ldc, bias, scale,
                                       M, N, K, wg / ntn, wg % ntn);
}

// ---------------- batched attention GEMM wrappers (4-wave core) ----------------
// qv: qv[b,s,(h,p)] = sum_t qh[h,s,t] * v[b,t,(h,p)]
__global__ __launch_bounds__(256) void qv_k(const __bf16* __restrict__ qhb,
                                            const __bf16* __restrict__ vT,
                                            __bf16* __restrict__ qvcat)
{
    const int bh = blockIdx.z, b = bh >> 3, h = bh & 7;
    gemm_core<2, 2, false, false>(qhb + (long)h * SLAB, SP_,
                                  vT + (long)bh * 64 * SP_, SP_,
                                  qvcat + (long)b * S_ * E_ + h * 64, E_,
                                  nullptr, 1.f, S_, 64, SP_, blockIdx.x, 0);
}

// scores: a[i,j] = scale * k[b,h,i,:] . qv[b,h,j,:]   (k lives in kvcat cols 0..511)
__global__ __launch_bounds__(256) void scores_k(const __bf16* __restrict__ kvcat,
                                                const __bf16* __restrict__ qvcat,
                                                __bf16* __restrict__ attnb)
{
    const int bh = blockIdx.z, b = bh >> 3, h = bh & 7;
    gemm_core<2, 2, false, false>(kvcat + (long)b * S_ * 1024 + h * 64, 1024,
                                  qvcat + (long)b * S_ * E_ + h * 64, E_,
                                  attnb + (long)bh * SLAB, SP_,
                                  nullptr, INV_SQRT_E, S_, S_, 64,
                                  blockIdx.x, blockIdx.y);
}

// av: o[i,(h,p)] = sum_j a[i,j] * v[b,j,(h,p)]
__global__ __launch_bounds__(256) void av_k(const __bf16* __restrict__ attnb,
                                            const __bf16* __restrict__ vT,
                                            __bf16* __restrict__ ocat)
{
    const int bh = blockIdx.z, b = bh >> 3, h = bh & 7;
    gemm_core<2, 2, false, false>(attnb + (long)bh * SLAB, SP_,
                                  vT + (long)bh * 64 * SP_, SP_,
                                  ocat + (long)b * S_ * E_ + h * 64, E_,
                                  nullptr, 1.f, S_, 64, SP_, blockIdx.x, 0);
}

// ---------------- softmax: one wave per 257-row, 4 rows/block ----------------
__global__ void softmax_kernel(__bf16* __restrict__ attnb)
{
    const int rowid = blockIdx.x * 4 + (threadIdx.x >> 6);   // grid 8224 exact
    const int lane  = threadIdx.x & 63;
    const int bh = rowid / S_, s = rowid % S_;
    __bf16* p = attnb + (long)bh * SLAB + (long)s * SP_;
    const float v0 = (float)p[lane],       v1 = (float)p[lane + 64];
    const float v2 = (float)p[lane + 128], v3 = (float)p[lane + 192];
    const float vx = (lane == 0) ? (float)p[256] : -1e30f;
    float m = fmaxf(fmaxf(fmaxf(v0, v1), fmaxf(v2, v3)), vx);
#pragma unroll
    for (int o = 32; o; o >>= 1) m = fmaxf(m, __shfl_xor(m, o));
    const float e0 = __expf(v0 - m), e1 = __expf(v1 - m);
    const float e2 = __expf(v2 - m), e3 = __expf(v3 - m);
    const float ex = (lane == 0) ? __expf(vx - m) : 0.f;
    float su = e0 + e1 + e2 + e3 + ex;
#pragma unroll
    for (int o = 32; o; o >>= 1) su += __shfl_xor(su, o);
    const float inv = 1.f / su;
    p[lane]       = (__bf16)(e0 * inv);
    p[lane + 64]  = (__bf16)(e1 * inv);
    p[lane + 128] = (__bf16)(e2 * inv);
    p[lane + 192] = (__bf16)(e3 * inv);
    if (lane == 0) p[256] = (__bf16)(ex * inv);
    if (lane >= 1 && lane < 32) p[256 + lane] = (__bf16)0.f;   // zero K-pad
}

// ---------------- LayerNorm: one wave per row (E=512, 8 elems/lane) ----------------
__global__ void ln_kernel(const float* __restrict__ x, const float* __restrict__ r,
                          const float* __restrict__ g, const float* __restrict__ bb,
                          float* __restrict__ outf, __bf16* __restrict__ outb,
                          int skip_cond, int nrows)
{
    const int row = blockIdx.x * 4 + (threadIdx.x >> 6);
    if (row >= nrows) return;
    const int lane = threadIdx.x & 63;
    const long xrow = skip_cond ? (long)row + (row >> 8) + 1 : (long)row;
    const float4* xr = (const float4*)(x + xrow * E_) + lane * 2;
    float4 a = xr[0], b4 = xr[1];
    if (r) {
        const float4* rr = (const float4*)(r + (long)row * E_) + lane * 2;
        const float4 c = rr[0], d = rr[1];
        a.x += c.x; a.y += c.y; a.z += c.z; a.w += c.w;
        b4.x += d.x; b4.y += d.y; b4.z += d.z; b4.w += d.w;
    }
    float e[8] = {a.x, a.y, a.z, a.w, b4.x, b4.y, b4.z, b4.w};
    float s = 0.f;
#pragma unroll
    for (int i = 0; i < 8; ++i) s += e[i];
#pragma unroll
    for (int o = 32; o; o >>= 1) s += __shfl_xor(s, o);
    const float mean = s * (1.f / 512.f);
    float v = 0.f;
#pragma unroll
    for (int i = 0; i < 8; ++i) { e[i] -= mean; v += e[i] * e[i]; }
#pragma unroll
    for (int o = 32; o; o >>= 1) v += __shfl_xor(v, o);
    const float inv = rsqrtf(v * (1.f / 512.f) + 1e-5f);
    const float4* gp = (const float4*)g + lane * 2;
    const float4* bp = (const float4*)bb + lane * 2;
    const float4 g0 = gp[0], g1 = gp[1], bb0 = bp[0], bb1 = bp[1];
    const float gv[8] = {g0.x, g0.y, g0.z, g0.w, g1.x, g1.y, g1.z, g1.w};
    const float bv[8] = {bb0.x, bb0.y, bb0.z, bb0.w, bb1.x, bb1.y, bb1.z, bb1.w};
    float o8[8];
#pragma unroll
    for (int i = 0; i < 8; ++i) o8[i] = e[i] * inv * gv[i] + bv[i];
    if (outf) {
        float4* of = (float4*)(outf + (long)row * E_) + lane * 2;
        of[0] = make_float4(o8[0], o8[1], o8[2], o8[3]);
        of[1] = make_float4(o8[4], o8[5], o8[6], o8[7]);
    }
    if (outb) {
        bf16x8 ov;
#pragma unroll
        for (int i = 0; i < 8; ++i) ov[i] = (__bf16)o8[i];
        *reinterpret_cast<bf16x8*>(outb + (long)row * E_ + lane * 8) = ov;
    }
}

// ---------------- converts / data movement ----------------
__global__ void conv_straight(const float* __restrict__ in, __bf16* __restrict__ out, long n)
{
    const long i = (long)blockIdx.x * 256 + threadIdx.x;
    if (i < n) out[i] = (__bf16)in[i];
}

// LDS-tiled transpose: out[bt][c*R + r] = in[bt][r*C + c]  (fp32 -> bf16)
__global__ void conv_transpose(const float* __restrict__ in, __bf16* __restrict__ out,
                               int R, int C, long in_bs, long out_bs)
{
    __shared__ float tile[32][33];
    const int bt = blockIdx.z;
    const float* ip = in + (long)bt * in_bs;
    __bf16* op = out + (long)bt * out_bs;
    const int r0 = blockIdx.x * 32, c0 = blockIdx.y * 32;
    const int tx = threadIdx.x & 31, ty = threadIdx.x >> 5;
#pragma unroll
    for (int i = 0; i < 32; i += 8) {
        const int rr = r0 + ty + i, cc = c0 + tx;
        tile[ty + i][tx] = (rr < R && cc < C) ? ip[(long)rr * C + cc] : 0.f;
    }
    __syncthreads();
#pragma unroll
    for (int i = 0; i < 32; i += 8) {
        const int cc = c0 + ty + i, rr = r0 + tx;
        if (cc < C && rr < R) op[(long)cc * R + rr] = (__bf16)tile[tx][ty + i];
    }
}

// all 5 per-layer weight transposes in one launch; grid (1024, 5)
__global__ void wconv_kernel(const float* __restrict__ kp, const float* __restrict__ vp,
                             const float* __restrict__ lift, const float* __restrict__ w1,
                             const float* __restrict__ w2,
                             __bf16* __restrict__ kvT, __bf16* __restrict__ liftT,
                             __bf16* __restrict__ w1T, __bf16* __restrict__ w2T)
{
    const int j = blockIdx.y;
    const float* src; __bf16* dst; int R, C, nb;
    switch (j) {
        case 0:  src = kp;   dst = kvT;          R = 512;  C = 64;   nb = 8; break;
        case 1:  src = vp;   dst = kvT + 262144; R = 512;  C = 64;   nb = 8; break;
        case 2:  src = lift; dst = liftT;        R = 512;  C = 512;  nb = 1; break;
        case 3:  src = w1;   dst = w1T;          R = 512;  C = 2048; nb = 1; break;
        default: src = w2;   dst = w2T;          R = 2048; C = 512;  nb = 1; break;
    }
    const int tR = R >> 5, tC = C >> 5;                 // dims all mult of 32
    int t = blockIdx.x;
    if (t >= tR * tC * nb) return;
    const int bt = t / (tR * tC);
    t %= tR * tC;
    const int rt = t / tC, ct = t % tC;
    const long bs = (long)R * C;
    const float* ip = src + (long)bt * bs;
    __bf16* op = dst + (long)bt * bs;
    __shared__ float tile[32][33];
    const int tx = threadIdx.x & 31, ty = threadIdx.x >> 5;
#pragma unroll
    for (int i = 0; i < 32; i += 8)
        tile[ty + i][tx] = ip[(long)(rt * 32 + ty + i) * C + ct * 32 + tx];
    __syncthreads();
#pragma unroll
    for (int i = 0; i < 32; i += 8)
        op[(long)(ct * 32 + ty + i) * R + rt * 32 + tx] = (__bf16)tile[tx][ty + i];
}

// qh (8,257,257) fp32 -> (8,288,288) bf16 zero-padded slabs
__global__ void conv_qh(const float* __restrict__ qh, __bf16* __restrict__ out)
{
    const long n = 8L * SLAB;
    for (long o = (long)blockIdx.x * 256 + threadIdx.x; o < n; o += (long)gridDim.x * 256) {
        const int t = (int)(o % SP_);
        const long rr = o / SP_;
        const int s = (int)(rr % SP_);
        const int h = (int)(rr / SP_);
        float v = 0.f;
        if (s < S_ && t < S_) v = qh[((long)h * S_ + s) * S_ + t];
        out[o] = (__bf16)v;
    }
}

// vT[bh][p][t] = kvcat[b*257+t][512 + h*64+p], zero for t>=257 (LDS-tiled)
// grid (9, 2, 128)
__global__ void vtrans_kernel(const __bf16* __restrict__ kvcat, __bf16* __restrict__ vT)
{
    __shared__ __bf16 tile[32][33];
    const int bh = blockIdx.z, b = bh >> 3, h = bh & 7;
    const int t0 = blockIdx.x * 32, p0 = blockIdx.y * 32;
    const int tx = threadIdx.x & 31, ty = threadIdx.x >> 5;
#pragma unroll
    for (int i = 0; i < 32; i += 8) {
        const int t = t0 + ty + i;
        tile[ty + i][tx] = (t < S_) ?
            kvcat[((long)(b * S_ + t)) * 1024 + 512 + h * 64 + p0 + tx] : (__bf16)0.f;
    }
    __syncthreads();
#pragma unroll
    for (int i = 0; i < 32; i += 8)
        vT[(long)bh * 64 * SP_ + (long)(p0 + ty + i) * SP_ + t0 + tx] = tile[tx][ty + i];
}

// im2col -> bf16
__global__ void im2col_kernel(const float* __restrict__ x, __bf16* __restrict__ xcol)
{
    const int idx = blockIdx.x * 256 + threadIdx.x;
    if (idx >= MTOK * 192) return;
    const int m = idx / 192, k = idx % 192;
    const int b = m >> 8, t = m & 255;
    const int ph = t >> 4, pw = t & 15;
    const int c = k >> 6, rr = k & 63;
    const int p = rr >> 3, q = rr & 7;
    xcol[idx] = (__bf16)x[(((long)(b * C_ + c) * HIMG) + ph * 8 + p) * HIMG + pw * 8 + q];
}

// cond MLP (two layers) + pos -> z row 0 (fp32 + bf16)
__global__ void cond_kernel(const float* __restrict__ y,
                            const float* __restrict__ w1, const float* __restrict__ b1,
                            const float* __restrict__ w2, const float* __restrict__ b2,
                            const float* __restrict__ pos,
                            float* __restrict__ z, __bf16* __restrict__ zb)
{
    __shared__ float c1[512];
    const int b = blockIdx.x;
    const int e = threadIdx.x;   // 512
    float v = y[b * 3 + 0] * w1[e] + y[b * 3 + 1] * w1[512 + e]
            + y[b * 3 + 2] * w1[1024 + e] + b1[e];
    v = v > 0.f ? v : 0.2f * v;
    c1[e] = v;
    __syncthreads();
    float acc = b2[e];
    for (int k = 0; k < 512; ++k) acc += c1[k] * w2[k * 512 + e];
    acc = acc > 0.f ? acc : 0.2f * acc;
    const float o = acc + pos[e];
    z[(long)b * S_ * E_ + e] = o;
    zb[(long)b * S_ * E_ + e] = (__bf16)o;
}

// z[b,1+t,e] = tok[(b*256+t)*512+e] + pos[(1+t)*512+e]  (fp32 + bf16)
__global__ void assemble_kernel(const float* __restrict__ tok,
                                const float* __restrict__ pos,
                                float* __restrict__ z, __bf16* __restrict__ zb)
{
    const int idx = blockIdx.x * 256 + threadIdx.x;
    if (idx >= MTOK * E_) return;
    const int m = idx >> 9;
    const int e = idx & 511;
    const int b = m >> 8, t = m & 255;
    const float o = tok[idx] + pos[(1 + t) * E_ + e];
    const long zi = ((long)b * S_ + 1 + t) * E_ + e;
    z[zi] = o;
    zb[zi] = (__bf16)o;
}

// scatter deconv tmp -> (B,C,H,W) + bias
__global__ void scatter_kernel(const float* __restrict__ dtmp,
                               const float* __restrict__ db,
                               float* __restrict__ out)
{
    const int idx = blockIdx.x * 256 + threadIdx.x;
    if (idx >= B_ * C_ * HIMG * HIMG) return;
    const int b  = idx / (C_ * HIMG * HIMG);
    const int rm = idx % (C_ * HIMG * HIMG);
    const int c  = rm / (HIMG * HIMG);
    const int hh = (rm % (HIMG * HIMG)) / HIMG;
    const int ww = rm % HIMG;
    const int ph = hh >> 3, p = hh & 7;
    const int pw = ww >> 3, q = ww & 7;
    out[idx] = dtmp[((long)(b * 256 + ph * 16 + pw)) * 192 + c * 64 + p * 8 + q] + db[c];
}

// ---------------- host launch ----------------
extern "C" void kernel_launch(void* const* d_in, const int* in_sizes, int n_in,
                              void* d_out, int out_size, void* d_ws, size_t ws_size,
                              hipStream_t stream)
{
    const float* x        = (const float*)d_in[0];
    const float* y        = (const float*)d_in[1];
    const float* patch_w  = (const float*)d_in[2];
    const float* patch_b  = (const float*)d_in[3];
    const float* cond_w1  = (const float*)d_in[4];
    const float* cond_b1  = (const float*)d_in[5];
    const float* cond_w2  = (const float*)d_in[6];
    const float* cond_b2  = (const float*)d_in[7];
    const float* pos      = (const float*)d_in[8];
    const float* enc_vp   = (const float*)d_in[9];
    const float* enc_kp   = (const float*)d_in[10];
    const float* enc_qh   = (const float*)d_in[11];
    const float* enc_lift = (const float*)d_in[12];
    const float* enc_ln1g = (const float*)d_in[13];
    const float* enc_ln1b = (const float*)d_in[14];
    const float* enc_w1   = (const float*)d_in[15];
    const float* enc_b1   = (const float*)d_in[16];
    const float* enc_w2   = (const float*)d_in[17];
    const float* enc_b2   = (const float*)d_in[18];
    const float* enc_ln2g = (const float*)d_in[19];
    const float* enc_ln2b = (const float*)d_in[20];
    const float* dec_vp   = (const float*)d_in[21];
    const float* dec_kp   = (const float*)d_in[22];
    const float* dec_qh   = (const float*)d_in[23];
    const float* dec_lift = (const float*)d_in[24];
    const float* dec_ln2g = (const float*)d_in[25];
    const float* dec_ln2b = (const float*)d_in[26];
    const float* dec_w1   = (const float*)d_in[27];
    const float* dec_b1   = (const float*)d_in[28];
    const float* dec_w2   = (const float*)d_in[29];
    const float* dec_b2   = (const float*)d_in[30];
    const float* dec_ln3g = (const float*)d_in[31];
    const float* dec_ln3b = (const float*)d_in[32];
    const float* final_g  = (const float*)d_in[33];
    const float* final_b  = (const float*)d_in[34];
    const float* deconv_w = (const float*)d_in[35];
    const float* deconv_b = (const float*)d_in[36];
    float* out = (float*)d_out;

    // ---- workspace carve-up (64B-aligned) ----
    char* wp = (char*)d_ws;
    auto alloc_f32 = [&](long n) { float* p = (float*)wp; wp += ((n * 4 + 63) & ~63LL); return p; };
    auto alloc_bf  = [&](long n) { __bf16* p = (__bf16*)wp; wp += ((n * 2 + 63) & ~63LL); return p; };

    float*  z      = alloc_f32(2105344);            // (B*S,512) fp32
    float*  tok    = alloc_f32(2097152);
    float*  res    = alloc_f32(2105344);
    float*  dtmp   = alloc_f32(786432);
    __bf16* zb     = alloc_bf(4352L * 512);
    __bf16* xcolb  = alloc_bf(786432);
    __bf16* kvcat  = alloc_bf(4352L * 1024);        // k cols 0..511, v cols 512..1023
    __bf16* qvcat  = alloc_bf(4352L * 512);
    __bf16* ocat   = alloc_bf(4352L * 512);
    __bf16* vT     = alloc_bf(128L * 64 * SP_);
    __bf16* attnb  = alloc_bf(128L * SLAB + 96L * SP_);
    __bf16* hidden = alloc_bf(4224L * 2048);
    __bf16* gbuf   = alloc_bf(4096L * 512);
    __bf16* pwb    = alloc_bf(512L * 192);
    __bf16* dwTb   = alloc_bf(192L * 512);
    __bf16* kvTb   = alloc_bf(1024L * 512);         // [kpT ; vpT]
    __bf16* liftTb = alloc_bf(262144);
    __bf16* w1Tb   = alloc_bf(1048576);             // (2048,512)
    __bf16* w2Tb   = alloc_bf(1048576);             // (512,2048)
    __bf16* qhb    = alloc_bf(8L * SLAB + 96L * SP_);
    (void)ws_size; (void)in_sizes; (void)n_in; (void)out_size;

    const dim3 blk(256);

    // ---- static weight converts ----
    conv_straight<<<dim3(384), blk, 0, stream>>>(patch_w, pwb, 98304);
    conv_transpose<<<dim3(16, 6, 1), blk, 0, stream>>>(deconv_w, dwTb, 512, 192, 0, 0);

    // ---- patch embedding + cond + assemble ----
    im2col_kernel<<<dim3(3072), blk, 0, stream>>>(x, xcolb);
    gemm_k<2, 2, false, true><<<dim3(256), blk, 0, stream>>>(
        xcolb, 192, pwb, 192, tok, 512, patch_b, 1.f, MTOK, 512, 192, 8);
    cond_kernel<<<dim3(B_), dim3(512), 0, stream>>>(y, cond_w1, cond_b1,
                                                    cond_w2, cond_b2, pos, z, zb);
    assemble_kernel<<<dim3(8192), blk, 0, stream>>>(tok, pos, z, zb);

    for (int l = 0; l < 12; ++l) {
        const bool enc = l < 6;
        const int  li  = enc ? l : l - 6;
        const float* vp   = (enc ? enc_vp   : dec_vp)   + (long)li * NH_ * E_ * 64;
        const float* kp   = (enc ? enc_kp   : dec_kp)   + (long)li * NH_ * E_ * 64;
        const float* qh   = (enc ? enc_qh   : dec_qh)   + (long)li * NH_ * S_ * S_;
        const float* lift = (enc ? enc_lift : dec_lift) + (long)li * 512 * 512;
        const float* g1   = (enc ? enc_ln1g : dec_ln2g) + li * E_;
        const float* bb1  = (enc ? enc_ln1b : dec_ln2b) + li * E_;
        const float* w1   = (enc ? enc_w1   : dec_w1)   + (long)li * E_ * HID_;
        const float* fb1  = (enc ? enc_b1   : dec_b1)   + li * HID_;
        const float* w2   = (enc ? enc_w2   : dec_w2)   + (long)li * HID_ * E_;
        const float* fb2  = (enc ? enc_b2   : dec_b2)   + li * E_;
        const float* g2   = (enc ? enc_ln2g : dec_ln3g) + li * E_;
        const float* bb2  = (enc ? enc_ln2b : dec_ln3b) + li * E_;

        // per-layer weight converts: one launch for all 5 transposes + qh pad
        wconv_kernel<<<dim3(1024, 5), blk, 0, stream>>>(kp, vp, lift, w1, w2,
                                                        kvTb, liftTb, w1Tb, w2Tb);
        conv_qh<<<dim3(2592), blk, 0, stream>>>(qh, qhb);

        // attention
        gemm_k<2, 4, false, false><<<dim3(264), dim3(512), 0, stream>>>(
            zb, 512, kvTb, 512, kvcat, 1024, nullptr, 1.f, MSEQ, 1024, 512, 8);
        vtrans_kernel<<<dim3(9, 2, 128), blk, 0, stream>>>(kvcat, vT);
        qv_k<<<dim3(3, 1, 128), blk, 0, stream>>>(qhb, vT, qvcat);
        scores_k<<<dim3(3, 5, 128), blk, 0, stream>>>(kvcat, qvcat, attnb);
        softmax_kernel<<<dim3(8224), blk, 0, stream>>>(attnb);
        av_k<<<dim3(3, 1, 128), blk, 0, stream>>>(attnb, vT, ocat);
        gemm_k<2, 2, false, true><<<dim3(264), blk, 0, stream>>>(
            ocat, 512, liftTb, 512, res, 512, nullptr, 1.f, MSEQ, 512, 512, 8);
        ln_kernel<<<dim3(1028), blk, 0, stream>>>(z, res, g1, bb1, z, zb, 0, MSEQ);

        // FFN
        gemm_k<2, 4, true, false><<<dim3(528), dim3(512), 0, stream>>>(
            zb, 512, w1Tb, 512, hidden, 2048, fb1, 1.f, MSEQ, HID_, 512, 16);
        gemm_k<2, 2, false, true><<<dim3(264), blk, 0, stream>>>(
            hidden, 2048, w2Tb, 2048, res, 512, fb2, 1.f, MSEQ, 512, HID_, 8);
        ln_kernel<<<dim3(1028), blk, 0, stream>>>(z, res, g2, bb2, z, zb, 0, MSEQ);
    }

    // final LN (drop cond token) -> bf16 grid
    ln_kernel<<<dim3(1024), blk, 0, stream>>>(z, nullptr, final_g, final_b,
                                              nullptr, gbuf, 1, MTOK);
    // deconv GEMM + scatter
    gemm_k<2, 2, false, true><<<dim3(96), blk, 0, stream>>>(
        gbuf, 512, dwTb, 512, dtmp, 192, nullptr, 1.f, MTOK, 192, 512, 3);
    scatter_kernel<<<dim3(3072), blk, 0, stream>>>(dtmp, deconv_b, out);
}